// Round 3
// baseline (971.543 us; speedup 1.0000x reference)
//
#include <hip/hip_runtime.h>

#define SDIM 10
#define HDIM 2048
#define LDIM 4096
#define BDIM 4

// 1/sqrt(2048)
#define KSCALE 0.02209708691207961f

// ---------------------------------------------------------------------------
// Kernel 1: k[b,s,o] = sum_h h_l[b,s,h]*w_k[o,h];  v likewise with w_v.
// Block = 512 threads = 8 waves = (4 b) x (2 s-halves); all waves share the
// same 4 o-rows of w_k AND w_v (weights read ONCE chip-wide, L1-shared).
// Wave: lane covers h (coalesced float4), 4 o x 5 s x 2 mats = 40 accs,
// 6-level butterfly. grid x = 512 o-groups (4 o each) -> 2 blocks/CU.
// ---------------------------------------------------------------------------
__global__ __launch_bounds__(512) void kv_kernel(
    const float* __restrict__ h_l, const float* __restrict__ w_k,
    const float* __restrict__ w_v, float* __restrict__ k_out,
    float* __restrict__ v_out) {
  const int wave = threadIdx.x >> 6;
  const int lane = threadIdx.x & 63;
  const int b = wave & 3;
  const int s0 = (wave >> 2) * 5;
  const int og = blockIdx.x;            // o-group: rows og*4 .. og*4+3

  const float4* hl4 = (const float4*)(h_l + (size_t)b * SDIM * HDIM);
  const float4* wk4[4];
  const float4* wv4[4];
#pragma unroll
  for (int o = 0; o < 4; o++) {
    wk4[o] = (const float4*)(w_k + (size_t)(og * 4 + o) * HDIM);
    wv4[o] = (const float4*)(w_v + (size_t)(og * 4 + o) * HDIM);
  }

  float ak[4][5], av[4][5];
#pragma unroll
  for (int o = 0; o < 4; o++)
#pragma unroll
    for (int s = 0; s < 5; s++) { ak[o][s] = 0.f; av[o][s] = 0.f; }

#pragma unroll
  for (int j = 0; j < 8; j++) {
    const int idx = j * 64 + lane;
    float4 wk[4], wv[4], hv[5];
#pragma unroll
    for (int o = 0; o < 4; o++) { wk[o] = wk4[o][idx]; wv[o] = wv4[o][idx]; }
#pragma unroll
    for (int s = 0; s < 5; s++) hv[s] = hl4[(size_t)(s0 + s) * 512 + idx];
#pragma unroll
    for (int o = 0; o < 4; o++)
#pragma unroll
      for (int s = 0; s < 5; s++) {
        ak[o][s] += wk[o].x * hv[s].x + wk[o].y * hv[s].y +
                    wk[o].z * hv[s].z + wk[o].w * hv[s].w;
        av[o][s] += wv[o].x * hv[s].x + wv[o].y * hv[s].y +
                    wv[o].z * hv[s].z + wv[o].w * hv[s].w;
      }
  }

#pragma unroll
  for (int o = 0; o < 4; o++)
#pragma unroll
    for (int s = 0; s < 5; s++) {
      float vk = ak[o][s], vv = av[o][s];
#pragma unroll
      for (int d = 1; d < 64; d <<= 1) {
        vk += __shfl_xor(vk, d);
        vv += __shfl_xor(vv, d);
      }
      if (lane == 0) {
        const size_t base = ((size_t)b * SDIM + s0 + s) * HDIM + og * 4 + o;
        k_out[base] = vk;
        v_out[base] = vv;
      }
    }
}

// ---------------------------------------------------------------------------
// Kernel 2a: kk partials. kk[b,s,h] = sum_o k[b,s,o]*w_q[o,h].
// Output-stationary: thread -> float4 of h (w_q fully coalesced), k scalars
// broadcast from LDS. grid (2 h-tiles, 16 o-chunks of 128, 4 b) = 128 blocks.
// Same (ht,oc) for different b are 32 block-ids apart -> same XCD -> L2 reuse.
// ---------------------------------------------------------------------------
#define OSPLIT 16
__global__ __launch_bounds__(256) void kk_part_kernel(
    const float* __restrict__ k_in, const float* __restrict__ w_q,
    float* __restrict__ part) {
  const int ht = blockIdx.x;
  const int oc = blockIdx.y;
  const int b  = blockIdx.z;
  const int f4 = ht * 256 + threadIdx.x;  // float4 index in [0,512)

  __shared__ float ksh[SDIM * 128];
  for (int idx = threadIdx.x; idx < SDIM * 128; idx += 256) {
    const int s = idx >> 7, oo = idx & 127;
    ksh[idx] = k_in[((size_t)b * SDIM + s) * HDIM + oc * 128 + oo];
  }
  __syncthreads();

  float4 acc[SDIM];
#pragma unroll
  for (int s = 0; s < SDIM; s++) acc[s] = make_float4(0.f, 0.f, 0.f, 0.f);

  const float4* wq4 = (const float4*)w_q;
  for (int oo = 0; oo < 128; oo++) {
    const float4 w = wq4[(size_t)(oc * 128 + oo) * 512 + f4];
#pragma unroll
    for (int s = 0; s < SDIM; s++) {
      const float kv = ksh[s * 128 + oo];
      acc[s].x += kv * w.x; acc[s].y += kv * w.y;
      acc[s].z += kv * w.z; acc[s].w += kv * w.w;
    }
  }
#pragma unroll
  for (int s = 0; s < SDIM; s++)
    ((float4*)part)[(((size_t)oc * BDIM + b) * SDIM + s) * 512 + f4] = acc[s];
}

// Kernel 2b: reduce 16 partials -> kk. 20480 float4 outputs.
__global__ __launch_bounds__(256) void kk_reduce_kernel(
    const float* __restrict__ part, float* __restrict__ kk_out) {
  const int t = blockIdx.x * 256 + threadIdx.x;  // [0, 20480)
  const float4* p4 = (const float4*)part;
  float4 acc = make_float4(0.f, 0.f, 0.f, 0.f);
#pragma unroll
  for (int p = 0; p < OSPLIT; p++) {
    const float4 v = p4[(size_t)p * 20480 + t];
    acc.x += v.x; acc.y += v.y; acc.z += v.z; acc.w += v.w;
  }
  ((float4*)kk_out)[t] = acc;
}

// ---------------------------------------------------------------------------
// Kernel 3: vo[b,s,o] = sum_h v[b,s,h]*w_o[o,h]. Same structure as kernel 1
// (single matrix, 8 o-rows per block). grid x = 256 o-groups -> 1 block/CU.
// ---------------------------------------------------------------------------
__global__ __launch_bounds__(512) void vo_kernel(
    const float* __restrict__ v_in, const float* __restrict__ w_o,
    float* __restrict__ vo_out) {
  const int wave = threadIdx.x >> 6;
  const int lane = threadIdx.x & 63;
  const int b = wave & 3;
  const int s0 = (wave >> 2) * 5;
  const int og = blockIdx.x;            // o-group: rows og*8 .. og*8+7

  const float4* vb4 = (const float4*)(v_in + (size_t)b * SDIM * HDIM);
  const float4* wo4[8];
#pragma unroll
  for (int o = 0; o < 8; o++)
    wo4[o] = (const float4*)(w_o + (size_t)(og * 8 + o) * HDIM);

  float acc[8][5];
#pragma unroll
  for (int o = 0; o < 8; o++)
#pragma unroll
    for (int s = 0; s < 5; s++) acc[o][s] = 0.f;

#pragma unroll
  for (int j = 0; j < 8; j++) {
    const int idx = j * 64 + lane;
    float4 wo[8], hv[5];
#pragma unroll
    for (int o = 0; o < 8; o++) wo[o] = wo4[o][idx];
#pragma unroll
    for (int s = 0; s < 5; s++) hv[s] = vb4[(size_t)(s0 + s) * 512 + idx];
#pragma unroll
    for (int o = 0; o < 8; o++)
#pragma unroll
      for (int s = 0; s < 5; s++)
        acc[o][s] += wo[o].x * hv[s].x + wo[o].y * hv[s].y +
                     wo[o].z * hv[s].z + wo[o].w * hv[s].w;
  }

#pragma unroll
  for (int o = 0; o < 8; o++)
#pragma unroll
    for (int s = 0; s < 5; s++) {
      float v = acc[o][s];
#pragma unroll
      for (int d = 1; d < 64; d <<= 1) v += __shfl_xor(v, d);
      if (lane == 0)
        vo_out[((size_t)b * SDIM + s0 + s) * HDIM + og * 8 + o] = v;
    }
}

// ---------------------------------------------------------------------------
// Kernel 4 (main): block = 512 threads (8 waves), 2 rows/wave = 16 rows/block.
// kk then vo staged through 40KB LDS in s-halves (peak 40KB -> 2 blocks/CU
// at VGPR<=128). h_e held in registers across both phases: h_e read once,
// out written once. grid (256, 4) = 1024 blocks.
// ---------------------------------------------------------------------------
__global__ __launch_bounds__(512, 4) void attn_kernel(
    const float* __restrict__ h_e, const float* __restrict__ kk,
    const float* __restrict__ vo, const float* __restrict__ alpha_p,
    float* __restrict__ out) {
  __shared__ float4 lds4[2560];  // 40 KB: 5 rows x 512 float4
  const int b = blockIdx.y;
  const int wave = threadIdx.x >> 6;
  const int lane = threadIdx.x & 63;
  const int row0 = blockIdx.x * 16 + wave * 2;
  const float alpha = *alpha_p;
  const float4* kkb4 = (const float4*)(kk + (size_t)b * SDIM * HDIM);
  const float4* vob4 = (const float4*)(vo + (size_t)b * SDIM * HDIM);
  const size_t rowbase = ((size_t)b * LDIM + row0) * HDIM;

  // h_e rows in registers for the whole kernel (64 VGPRs)
  float4 he[2][8];
#pragma unroll
  for (int r = 0; r < 2; r++) {
    const float4* src = (const float4*)(h_e + rowbase + (size_t)r * HDIM);
#pragma unroll
    for (int i = 0; i < 8; i++) he[r][i] = src[i * 64 + lane];
  }

  float acc[2][SDIM];
#pragma unroll
  for (int r = 0; r < 2; r++)
#pragma unroll
    for (int s = 0; s < SDIM; s++) acc[r][s] = 0.f;

  // ---- scores: two LDS stages of kk (5 rows each) ----
  for (int half = 0; half < 2; half++) {
    __syncthreads();
    for (int t = threadIdx.x; t < 2560; t += 512) lds4[t] = kkb4[half * 2560 + t];
    __syncthreads();
#pragma unroll
    for (int i = 0; i < 8; i++)
#pragma unroll
      for (int s = 0; s < 5; s++) {
        const float4 kv = lds4[s * 512 + i * 64 + lane];
#pragma unroll
        for (int r = 0; r < 2; r++)
          acc[r][half * 5 + s] += he[r][i].x * kv.x + he[r][i].y * kv.y +
                                  he[r][i].z * kv.z + he[r][i].w * kv.w;
      }
  }

  // butterfly reduce across 64 lanes; every lane ends with the full sums
#pragma unroll
  for (int r = 0; r < 2; r++)
#pragma unroll
    for (int s = 0; s < SDIM; s++) {
      float v = acc[r][s];
      v += __shfl_xor(v, 1);
      v += __shfl_xor(v, 2);
      v += __shfl_xor(v, 4);
      v += __shfl_xor(v, 8);
      v += __shfl_xor(v, 16);
      v += __shfl_xor(v, 32);
      acc[r][s] = v * KSCALE;
    }

  // softmax over S=10, fold alpha
#pragma unroll
  for (int r = 0; r < 2; r++) {
    float m = acc[r][0];
#pragma unroll
    for (int s = 1; s < SDIM; s++) m = fmaxf(m, acc[r][s]);
    float sum = 0.f;
#pragma unroll
    for (int s = 0; s < SDIM; s++) {
      acc[r][s] = __expf(acc[r][s] - m);
      sum += acc[r][s];
    }
    const float inv = alpha / sum;
#pragma unroll
    for (int s = 0; s < SDIM; s++) acc[r][s] *= inv;
  }

  // ---- output: two LDS stages of vo; accumulate into he registers ----
  for (int half = 0; half < 2; half++) {
    __syncthreads();
    for (int t = threadIdx.x; t < 2560; t += 512) lds4[t] = vob4[half * 2560 + t];
    __syncthreads();
#pragma unroll
    for (int i = 0; i < 8; i++)
#pragma unroll
      for (int s = 0; s < 5; s++) {
        const float4 vv = lds4[s * 512 + i * 64 + lane];
#pragma unroll
        for (int r = 0; r < 2; r++) {
          const float p = acc[r][half * 5 + s];
          he[r][i].x += p * vv.x;
          he[r][i].y += p * vv.y;
          he[r][i].z += p * vv.z;
          he[r][i].w += p * vv.w;
        }
      }
  }

#pragma unroll
  for (int r = 0; r < 2; r++) {
    float4* dst = (float4*)(out + rowbase + (size_t)r * HDIM);
#pragma unroll
    for (int i = 0; i < 8; i++) dst[i * 64 + lane] = he[r][i];
  }
}

// ---------------------------------------------------------------------------
extern "C" void kernel_launch(void* const* d_in, const int* in_sizes, int n_in,
                              void* d_out, int out_size, void* d_ws, size_t ws_size,
                              hipStream_t stream) {
  const float* h_e   = (const float*)d_in[0];  // [4,4096,2048]
  const float* h_l   = (const float*)d_in[1];  // [4,10,2048]
  const float* w_q   = (const float*)d_in[2];  // [2048,2048]
  const float* w_k   = (const float*)d_in[3];
  const float* w_v   = (const float*)d_in[4];
  const float* w_o   = (const float*)d_in[5];
  const float* alpha = (const float*)d_in[6];  // scalar
  float* out = (float*)d_out;

  float* ws      = (float*)d_ws;
  float* k_ws    = ws;             // 81920 floats
  float* v_ws    = ws + 81920;
  float* kk_ws   = ws + 163840;
  float* vo_ws   = ws + 245760;
  float* part_ws = ws + 327680;    // 16*4*10*2048 = 1310720 floats (5.2 MB)

  kv_kernel<<<512, 512, 0, stream>>>(h_l, w_k, w_v, k_ws, v_ws);
  kk_part_kernel<<<dim3(2, OSPLIT, BDIM), 256, 0, stream>>>(k_ws, w_q, part_ws);
  kk_reduce_kernel<<<80, 256, 0, stream>>>(part_ws, kk_ws);
  vo_kernel<<<256, 512, 0, stream>>>(v_ws, w_o, vo_ws);
  attn_kernel<<<dim3(256, BDIM), 512, 0, stream>>>(h_e, kk_ws, vo_ws, alpha, out);
}

// Round 4
// 808.841 us; speedup vs baseline: 1.2012x; 1.2012x over previous
//
#include <hip/hip_runtime.h>

#define SDIM 10
#define HDIM 2048
#define LDIM 4096
#define BDIM 4

// 1/sqrt(2048)
#define KSCALE 0.02209708691207961f

// ---------------------------------------------------------------------------
// Kernel 1: k[b,s,o] = sum_h h_l[b,s,h]*w_k[o,h];  v likewise with w_v.
// One block per o-row; 4 waves = 4 batches share the same w_k/w_v row
// (weights read once chip-wide, L1-shared). lane -> h float4 (coalesced),
// small per-iter footprint (unroll 2), 20 accs/wave, 6-level butterfly.
// grid 2048, block 256.
// ---------------------------------------------------------------------------
__global__ __launch_bounds__(256) void kv_kernel(
    const float* __restrict__ h_l, const float* __restrict__ w_k,
    const float* __restrict__ w_v, float* __restrict__ k_out,
    float* __restrict__ v_out) {
  const int b = threadIdx.x >> 6;
  const int lane = threadIdx.x & 63;
  const int o = blockIdx.x;

  const float4* wk4 = (const float4*)(w_k + (size_t)o * HDIM);
  const float4* wv4 = (const float4*)(w_v + (size_t)o * HDIM);
  const float4* hl4 = (const float4*)(h_l + (size_t)b * SDIM * HDIM);

  float ak[SDIM], av[SDIM];
#pragma unroll
  for (int s = 0; s < SDIM; s++) { ak[s] = 0.f; av[s] = 0.f; }

#pragma unroll 2
  for (int j = 0; j < 8; j++) {
    const int idx = j * 64 + lane;
    const float4 wk = wk4[idx];
    const float4 wv = wv4[idx];
#pragma unroll
    for (int s = 0; s < SDIM; s++) {
      const float4 h = hl4[(size_t)s * 512 + idx];
      ak[s] += wk.x * h.x + wk.y * h.y + wk.z * h.z + wk.w * h.w;
      av[s] += wv.x * h.x + wv.y * h.y + wv.z * h.z + wv.w * h.w;
    }
  }

#pragma unroll
  for (int s = 0; s < SDIM; s++) {
    float vk = ak[s], vv = av[s];
#pragma unroll
    for (int d = 1; d < 64; d <<= 1) {
      vk += __shfl_xor(vk, d);
      vv += __shfl_xor(vv, d);
    }
    if (lane == 0) {
      const size_t base = ((size_t)b * SDIM + s) * HDIM + o;
      k_out[base] = vk;
      v_out[base] = vv;
    }
  }
}

// ---------------------------------------------------------------------------
// Kernel 2a: kk partials. kk[b,s,h] = sum_o k[b,s,o]*w_q[o,h].
// Output-stationary: thread -> one float4 of h (w_q fully coalesced),
// k scalars broadcast from LDS. grid (4 h-tiles of 128 f4, 16 o-chunks of
// 128 rows, 4 b) = 256 blocks x 128 threads; each block streams 256 KB of
// w_q. Partials (OSPLIT=16) to ws.
// ---------------------------------------------------------------------------
#define OSPLIT 16
__global__ __launch_bounds__(128) void kk_part_kernel(
    const float* __restrict__ k_in, const float* __restrict__ w_q,
    float* __restrict__ part) {
  const int ht = blockIdx.x;              // 0..3
  const int oc = blockIdx.y;              // 0..15
  const int b  = blockIdx.z;
  const int f4 = ht * 128 + threadIdx.x;  // float4 index in [0,512)

  __shared__ float ksh[SDIM * 128];
  for (int idx = threadIdx.x; idx < SDIM * 128; idx += 128) {
    const int s = idx >> 7, oo = idx & 127;
    ksh[idx] = k_in[((size_t)b * SDIM + s) * HDIM + oc * 128 + oo];
  }
  __syncthreads();

  float4 acc[SDIM];
#pragma unroll
  for (int s = 0; s < SDIM; s++) acc[s] = make_float4(0.f, 0.f, 0.f, 0.f);

  const float4* wq4 = (const float4*)w_q;
#pragma unroll 8
  for (int oo = 0; oo < 128; oo++) {
    const float4 w = wq4[(size_t)(oc * 128 + oo) * 512 + f4];
#pragma unroll
    for (int s = 0; s < SDIM; s++) {
      const float kv = ksh[s * 128 + oo];
      acc[s].x += kv * w.x; acc[s].y += kv * w.y;
      acc[s].z += kv * w.z; acc[s].w += kv * w.w;
    }
  }
#pragma unroll
  for (int s = 0; s < SDIM; s++)
    ((float4*)part)[(((size_t)oc * BDIM + b) * SDIM + s) * 512 + f4] = acc[s];
}

// Kernel 2b: reduce 16 partials -> kk. 20480 float4 outputs.
__global__ __launch_bounds__(256) void kk_reduce_kernel(
    const float* __restrict__ part, float* __restrict__ kk_out) {
  const int t = blockIdx.x * 256 + threadIdx.x;  // [0, 20480)
  const float4* p4 = (const float4*)part;
  float4 acc = make_float4(0.f, 0.f, 0.f, 0.f);
#pragma unroll
  for (int p = 0; p < OSPLIT; p++) {
    const float4 v = p4[(size_t)p * 20480 + t];
    acc.x += v.x; acc.y += v.y; acc.z += v.z; acc.w += v.w;
  }
  ((float4*)kk_out)[t] = acc;
}

// ---------------------------------------------------------------------------
// Kernel 3: vo[b,s,o] = sum_h v[b,s,h]*w_o[o,h]. Same structure as kernel 1,
// single matrix. grid 2048, block 256 (4 waves = 4 batches, shared w_o row).
// ---------------------------------------------------------------------------
__global__ __launch_bounds__(256) void vo_kernel(
    const float* __restrict__ v_in, const float* __restrict__ w_o,
    float* __restrict__ vo_out) {
  const int b = threadIdx.x >> 6;
  const int lane = threadIdx.x & 63;
  const int o = blockIdx.x;

  const float4* wo4 = (const float4*)(w_o + (size_t)o * HDIM);
  const float4* vb4 = (const float4*)(v_in + (size_t)b * SDIM * HDIM);

  float acc[SDIM];
#pragma unroll
  for (int s = 0; s < SDIM; s++) acc[s] = 0.f;

#pragma unroll 2
  for (int j = 0; j < 8; j++) {
    const int idx = j * 64 + lane;
    const float4 wo = wo4[idx];
#pragma unroll
    for (int s = 0; s < SDIM; s++) {
      const float4 h = vb4[(size_t)s * 512 + idx];
      acc[s] += wo.x * h.x + wo.y * h.y + wo.z * h.z + wo.w * h.w;
    }
  }

#pragma unroll
  for (int s = 0; s < SDIM; s++) {
    float v = acc[s];
#pragma unroll
    for (int d = 1; d < 64; d <<= 1) v += __shfl_xor(v, d);
    if (lane == 0)
      vo_out[((size_t)b * SDIM + s) * HDIM + o] = v;
  }
}

// ---------------------------------------------------------------------------
// Kernel 4 (main): block 256 (4 waves), 2 rows/wave = 8 rows/block.
// kk then vo staged through 40KB LDS in 5-row halves. h_e held in registers
// across both phases (read once, written once). __launch_bounds__(256,4):
// VGPR cap 128 (round-2 config that compiled clean), 4 blocks/CU = 160KB LDS.
// grid (512, 4) = 2048 blocks.
// ---------------------------------------------------------------------------
__global__ __launch_bounds__(256, 4) void attn_kernel(
    const float* __restrict__ h_e, const float* __restrict__ kk,
    const float* __restrict__ vo, const float* __restrict__ alpha_p,
    float* __restrict__ out) {
  __shared__ float4 lds4[2560];  // 40 KB: 5 rows x 512 float4
  const int b = blockIdx.y;
  const int wave = threadIdx.x >> 6;
  const int lane = threadIdx.x & 63;
  const int row0 = blockIdx.x * 8 + wave * 2;
  const float alpha = *alpha_p;
  const float4* kkb4 = (const float4*)(kk + (size_t)b * SDIM * HDIM);
  const float4* vob4 = (const float4*)(vo + (size_t)b * SDIM * HDIM);
  const size_t rowbase = ((size_t)b * LDIM + row0) * HDIM;

  // h_e rows in registers for the whole kernel (64 VGPRs)
  float4 he[2][8];
#pragma unroll
  for (int r = 0; r < 2; r++) {
    const float4* src = (const float4*)(h_e + rowbase + (size_t)r * HDIM);
#pragma unroll
    for (int i = 0; i < 8; i++) he[r][i] = src[i * 64 + lane];
  }

  float acc[2][SDIM];
#pragma unroll
  for (int r = 0; r < 2; r++)
#pragma unroll
    for (int s = 0; s < SDIM; s++) acc[r][s] = 0.f;

  // ---- scores: two LDS stages of kk (5 rows each) ----
  for (int half = 0; half < 2; half++) {
    __syncthreads();
    for (int t = threadIdx.x; t < 2560; t += 256) lds4[t] = kkb4[half * 2560 + t];
    __syncthreads();
#pragma unroll
    for (int i = 0; i < 8; i++)
#pragma unroll
      for (int s = 0; s < 5; s++) {
        const float4 kv = lds4[s * 512 + i * 64 + lane];
#pragma unroll
        for (int r = 0; r < 2; r++)
          acc[r][half * 5 + s] += he[r][i].x * kv.x + he[r][i].y * kv.y +
                                  he[r][i].z * kv.z + he[r][i].w * kv.w;
      }
  }

  // butterfly reduce; every lane ends with the full sums
#pragma unroll
  for (int r = 0; r < 2; r++)
#pragma unroll
    for (int s = 0; s < SDIM; s++) {
      float v = acc[r][s];
      v += __shfl_xor(v, 1);
      v += __shfl_xor(v, 2);
      v += __shfl_xor(v, 4);
      v += __shfl_xor(v, 8);
      v += __shfl_xor(v, 16);
      v += __shfl_xor(v, 32);
      acc[r][s] = v * KSCALE;
    }

  // softmax over S=10, fold alpha
#pragma unroll
  for (int r = 0; r < 2; r++) {
    float m = acc[r][0];
#pragma unroll
    for (int s = 1; s < SDIM; s++) m = fmaxf(m, acc[r][s]);
    float sum = 0.f;
#pragma unroll
    for (int s = 0; s < SDIM; s++) {
      acc[r][s] = __expf(acc[r][s] - m);
      sum += acc[r][s];
    }
    const float inv = alpha / sum;
#pragma unroll
    for (int s = 0; s < SDIM; s++) acc[r][s] *= inv;
  }

  // ---- output: two LDS stages of vo; accumulate into he registers ----
  for (int half = 0; half < 2; half++) {
    __syncthreads();
    for (int t = threadIdx.x; t < 2560; t += 256) lds4[t] = vob4[half * 2560 + t];
    __syncthreads();
#pragma unroll
    for (int i = 0; i < 8; i++)
#pragma unroll
      for (int s = 0; s < 5; s++) {
        const float4 vv = lds4[s * 512 + i * 64 + lane];
#pragma unroll
        for (int r = 0; r < 2; r++) {
          const float p = acc[r][half * 5 + s];
          he[r][i].x += p * vv.x;
          he[r][i].y += p * vv.y;
          he[r][i].z += p * vv.z;
          he[r][i].w += p * vv.w;
        }
      }
  }

#pragma unroll
  for (int r = 0; r < 2; r++) {
    float4* dst = (float4*)(out + rowbase + (size_t)r * HDIM);
#pragma unroll
    for (int i = 0; i < 8; i++) dst[i * 64 + lane] = he[r][i];
  }
}

// ---------------------------------------------------------------------------
extern "C" void kernel_launch(void* const* d_in, const int* in_sizes, int n_in,
                              void* d_out, int out_size, void* d_ws, size_t ws_size,
                              hipStream_t stream) {
  const float* h_e   = (const float*)d_in[0];  // [4,4096,2048]
  const float* h_l   = (const float*)d_in[1];  // [4,10,2048]
  const float* w_q   = (const float*)d_in[2];  // [2048,2048]
  const float* w_k   = (const float*)d_in[3];
  const float* w_v   = (const float*)d_in[4];
  const float* w_o   = (const float*)d_in[5];
  const float* alpha = (const float*)d_in[6];  // scalar
  float* out = (float*)d_out;

  float* ws      = (float*)d_ws;
  float* k_ws    = ws;             // 81920 floats
  float* v_ws    = ws + 81920;
  float* kk_ws   = ws + 163840;
  float* vo_ws   = ws + 245760;
  float* part_ws = ws + 327680;    // 16*4*10*2048 = 1310720 floats (5.2 MB)

  kv_kernel<<<2048, 256, 0, stream>>>(h_l, w_k, w_v, k_ws, v_ws);
  kk_part_kernel<<<dim3(4, OSPLIT, BDIM), 128, 0, stream>>>(k_ws, w_q, part_ws);
  kk_reduce_kernel<<<80, 256, 0, stream>>>(part_ws, kk_ws);
  vo_kernel<<<2048, 256, 0, stream>>>(v_ws, w_o, vo_ws);
  attn_kernel<<<dim3(512, BDIM), 256, 0, stream>>>(h_e, kk_ws, vo_ws, alpha, out);
}